// Round 5
// baseline (471.675 us; speedup 1.0000x reference)
//
#include <hip/hip_runtime.h>

#define NB 32      // B
#define NS 8192    // S
#define NH 256     // H
#define NR 256     // RIN
#define NQ 256     // QIN

typedef __bf16 bf16x8 __attribute__((ext_vector_type(8)));
typedef float  f32x4  __attribute__((ext_vector_type(4)));

__device__ __forceinline__ float fast_tanh(float x) {
  // tanh(x) = (e^{2x}-1)/(e^{2x}+1); clamp: tanh(|x|>=15) == 1.0f in f32 exactly
  x = fminf(15.0f, fmaxf(-15.0f, x));
  float e = __expf(2.0f * x);
  return (e - 1.0f) * __builtin_amdgcn_rcpf(e + 1.0f);
}

// split 8 consecutive f32 into bf16 hi + bf16 lo (RNE): x ~= hi + lo, |err| ~ 2^-16 rel
__device__ __forceinline__ void split8(float4 a, float4 b, bf16x8& hi, bf16x8& lo) {
  float x[8] = {a.x, a.y, a.z, a.w, b.x, b.y, b.z, b.w};
#pragma unroll
  for (int j = 0; j < 8; ++j) {
    __bf16 h = (__bf16)x[j];
    hi[j] = h;
    lo[j] = (__bf16)(x[j] - (float)h);
  }
}

// blocks 0..31: q[b,h] = query[b,:]@Wq[h,:] + bq[h]
// blocks 32..63: split Wr into fragment-linear hi/lo bf16: [ks][mtile][lane][8]
//   element = Wr[16*mt + (l&15)][32*ks + 8*(l>>4) + j]  (A-frag layout of mfma 16x16x32)
__global__ __launch_bounds__(256) void prep_kernel(
    const float* __restrict__ query, const float* __restrict__ Wq,
    const float* __restrict__ bq, const float* __restrict__ Wr,
    float* __restrict__ ws_q, __bf16* __restrict__ wsAhi, __bf16* __restrict__ wsAlo) {
  const int tid = threadIdx.x;
  const int blk = blockIdx.x;
  if (blk < NB) {
    const float4* qr = reinterpret_cast<const float4*>(query + blk * NQ);
    const float4* wr = reinterpret_cast<const float4*>(Wq + tid * NQ);
    float acc = 0.0f;
#pragma unroll 8
    for (int i = 0; i < NQ / 4; ++i) {
      float4 a = qr[i], w = wr[i];
      acc += a.x * w.x + a.y * w.y + a.z * w.z + a.w * w.w;
    }
    ws_q[blk * NH + tid] = acc + bq[tid];
  } else {
    const int gid = (blk - NB) * 256 + tid;   // 0..8191 = [ks(8)][mt(16)][lane(64)]
    const int l  = gid & 63;
    const int mt = (gid >> 6) & 15;
    const int ks = gid >> 10;
    const int row = 16 * mt + (l & 15);
    const int kb  = 32 * ks + 8 * (l >> 4);
    const float4* src = reinterpret_cast<const float4*>(Wr + row * NR + kb);
    bf16x8 hi, lo;
    split8(src[0], src[1], hi, lo);
    *reinterpret_cast<bf16x8*>(wsAhi + (size_t)gid * 8) = hi;
    *reinterpret_cast<bf16x8*>(wsAlo + (size_t)gid * 8) = lo;
  }
}

// Epilogue-only barrier: publish LDS writes (lgkmcnt), no vmcnt drain.
__device__ __forceinline__ void barrier_no_vmem_drain() {
  asm volatile("s_waitcnt lgkmcnt(0)" ::: "memory");
  __builtin_amdgcn_sched_barrier(0);
  __builtin_amdgcn_s_barrier();
  __builtin_amdgcn_sched_barrier(0);
}

// R4: BARRIER-FREE main loop. Each wave loads its B-fragments directly from ref
// (per-lane 8 consecutive r = 2x float4 — exactly the MFMA B-frag layout) and
// splits f32->bf16 hi/lo in-register. No LDS staging, no __syncthreads in the
// k-loop; 4 waves read the same 8KB/iter tile -> L1 absorbs the redundancy.
// Block = batch b, 64 s-cols, all 256 h rows; wave wm owns h in [64wm, 64wm+64).
__global__ __launch_bounds__(256, 3) void attn_kernel(
    const float* __restrict__ ref, const float* __restrict__ br,
    const float* __restrict__ v, const float* __restrict__ ws_q,
    const __bf16* __restrict__ wsAhi, const __bf16* __restrict__ wsAlo,
    float* __restrict__ e_out, float* __restrict__ u_out) {
  __shared__ float u_part[4][64];

  const int tid = threadIdx.x;
  const int l   = tid & 63;
  const int wm  = tid >> 6;
  const int s0  = blockIdx.x * 64;
  const int b   = blockIdx.y;

  // per-nt B-frag source: lane l reads ref[s0+16nt+(l&15)][b][32ks + 8(l>>4) + 0..7]
  const float* pB0 = ref + (size_t)(s0 + 0  + (l & 15)) * (NB * NR) + (size_t)b * NR + 8 * (l >> 4);
  const float* pB1 = pB0 + (size_t)16 * NB * NR;
  const float* pB2 = pB1 + (size_t)16 * NB * NR;
  const float* pB3 = pB2 + (size_t)16 * NB * NR;

  f32x4 acc[4][4];
  const f32x4 zero = {0.f, 0.f, 0.f, 0.f};
#pragma unroll
  for (int mt = 0; mt < 4; ++mt)
#pragma unroll
    for (int nt = 0; nt < 4; ++nt) acc[mt][nt] = zero;

  // prologue: B data for ks=0
  float4 pb[4][2];
  pb[0][0] = *(const float4*)(pB0); pb[0][1] = *(const float4*)(pB0 + 4);
  pb[1][0] = *(const float4*)(pB1); pb[1][1] = *(const float4*)(pB1 + 4);
  pb[2][0] = *(const float4*)(pB2); pb[2][1] = *(const float4*)(pB2 + 4);
  pb[3][0] = *(const float4*)(pB3); pb[3][1] = *(const float4*)(pB3 + 4);

#pragma unroll 1
  for (int ks = 0; ks < NR / 32; ++ks) {
    // A-frags (L2-resident pre-split Wr), issued first; latency hides under split
    bf16x8 ah[4], al[4];
#pragma unroll
    for (int mt = 0; mt < 4; ++mt) {
      const size_t fo = ((size_t)(ks * 16 + wm * 4 + mt) * 64 + l) * 8;
      ah[mt] = *reinterpret_cast<const bf16x8*>(wsAhi + fo);
      al[mt] = *reinterpret_cast<const bf16x8*>(wsAlo + fo);
    }
    // split current B data (in regs since last iter) into bf16 hi/lo frags
    bf16x8 bh[4], bl[4];
#pragma unroll
    for (int nt = 0; nt < 4; ++nt) split8(pb[nt][0], pb[nt][1], bh[nt], bl[nt]);
    // issue next iter's B loads (clamped on last iter; redundant L1-hit reload)
    const int kn = (ks < NR / 32 - 1) ? (ks + 1) * 32 : ks * 32;
    pb[0][0] = *(const float4*)(pB0 + kn); pb[0][1] = *(const float4*)(pB0 + kn + 4);
    pb[1][0] = *(const float4*)(pB1 + kn); pb[1][1] = *(const float4*)(pB1 + kn + 4);
    pb[2][0] = *(const float4*)(pB2 + kn); pb[2][1] = *(const float4*)(pB2 + kn + 4);
    pb[3][0] = *(const float4*)(pB3 + kn); pb[3][1] = *(const float4*)(pB3 + kn + 4);

    __builtin_amdgcn_s_setprio(1);
#pragma unroll
    for (int mt = 0; mt < 4; ++mt) {
#pragma unroll
      for (int nt = 0; nt < 4; ++nt) {
        acc[mt][nt] = __builtin_amdgcn_mfma_f32_16x16x32_bf16(ah[mt], bh[nt], acc[mt][nt], 0, 0, 0);
        acc[mt][nt] = __builtin_amdgcn_mfma_f32_16x16x32_bf16(ah[mt], bl[nt], acc[mt][nt], 0, 0, 0);
        acc[mt][nt] = __builtin_amdgcn_mfma_f32_16x16x32_bf16(al[mt], bh[nt], acc[mt][nt], 0, 0, 0);
      }
    }
    __builtin_amdgcn_s_setprio(0);
  }

  // Epilogue. C/D layout (m89-verified): col = lane&15, row = 4*(lane>>4) + reg
  const int col = l & 15;
  const int rq  = l >> 4;
  float psum[4] = {0.f, 0.f, 0.f, 0.f};
#pragma unroll
  for (int mt = 0; mt < 4; ++mt) {
#pragma unroll
    for (int r = 0; r < 4; ++r) {
      const int h = 64 * wm + 16 * mt + 4 * rq + r;
      const float brv = br[h];
      const float qv  = ws_q[b * NH + h];
      const float vv  = v[h];
#pragma unroll
      for (int nt = 0; nt < 4; ++nt) {
        float e = acc[mt][nt][r] + brv;
        e_out[(size_t)b * NH * NS + (size_t)h * NS + (s0 + 16 * nt + col)] = e;
        psum[nt] += vv * fast_tanh(qv + e);
      }
    }
  }
  // reduce over h: butterfly over lane-quads, then cross-wave sum via LDS
#pragma unroll
  for (int nt = 0; nt < 4; ++nt) {
    float p = psum[nt];
    p += __shfl_xor(p, 16, 64);
    p += __shfl_xor(p, 32, 64);
    if (l < 16) u_part[wm][16 * nt + col] = p;
  }
  barrier_no_vmem_drain();   // publish u_part only; e-stores stay in flight
  if (tid < 64) {
    float u = u_part[0][tid] + u_part[1][tid] + u_part[2][tid] + u_part[3][tid];
    u_out[(size_t)b * NS + s0 + tid] = 10.0f * fast_tanh(u);
  }
}

extern "C" void kernel_launch(void* const* d_in, const int* in_sizes, int n_in,
                              void* d_out, int out_size, void* d_ws, size_t ws_size,
                              hipStream_t stream) {
  const float* query = (const float*)d_in[0];
  const float* ref   = (const float*)d_in[1];
  const float* Wq    = (const float*)d_in[2];
  const float* bq    = (const float*)d_in[3];
  const float* Wr    = (const float*)d_in[4];
  const float* br    = (const float*)d_in[5];
  const float* v     = (const float*)d_in[6];

  float* e_out = (float*)d_out;                       // [B][H][S]
  float* u_out = e_out + (size_t)NB * NH * NS;        // [B][S]

  // ws layout: q f32[32][256] (32 KiB) | Wr hi bf16[8192*8] (128 KiB) | Wr lo (128 KiB)
  float*  ws_q  = (float*)d_ws;
  __bf16* wsAhi = (__bf16*)((char*)d_ws + 32 * 1024);
  __bf16* wsAlo = (__bf16*)((char*)d_ws + 32 * 1024 + 128 * 1024);

  prep_kernel<<<dim3(NB + 32), 256, 0, stream>>>(query, Wq, bq, Wr, ws_q, wsAhi, wsAlo);
  attn_kernel<<<dim3(NS / 64, NB), 256, 0, stream>>>(ref, br, v, ws_q, wsAhi, wsAlo, e_out, u_out);
}

// Round 6
// 225.834 us; speedup vs baseline: 2.0886x; 2.0886x over previous
//
#include <hip/hip_runtime.h>

#define NB 32      // B
#define NS 8192    // S
#define NH 256     // H
#define NR 256     // RIN
#define NQ 256     // QIN

typedef __bf16 bf16x8 __attribute__((ext_vector_type(8)));
typedef __bf16 bf16x4 __attribute__((ext_vector_type(4)));
typedef float  f32x4  __attribute__((ext_vector_type(4)));

__device__ __forceinline__ float fast_tanh(float x) {
  // tanh(x) = (e^{2x}-1)/(e^{2x}+1); clamp: tanh(|x|>=15) == 1.0f in f32 exactly
  x = fminf(15.0f, fmaxf(-15.0f, x));
  float e = __expf(2.0f * x);
  return (e - 1.0f) * __builtin_amdgcn_rcpf(e + 1.0f);
}

// split 8 consecutive f32 into bf16 hi + bf16 lo (RNE): x ~= hi + lo
__device__ __forceinline__ void split8(float4 a, float4 b, bf16x8& hi, bf16x8& lo) {
  float x[8] = {a.x, a.y, a.z, a.w, b.x, b.y, b.z, b.w};
#pragma unroll
  for (int j = 0; j < 8; ++j) {
    __bf16 h = (__bf16)x[j];
    hi[j] = h;
    lo[j] = (__bf16)(x[j] - (float)h);
  }
}

// split 4 consecutive f32 into bf16 hi + lo
__device__ __forceinline__ void split4(float4 a, bf16x4& hi, bf16x4& lo) {
  float x[4] = {a.x, a.y, a.z, a.w};
#pragma unroll
  for (int j = 0; j < 4; ++j) {
    __bf16 h = (__bf16)x[j];
    hi[j] = h;
    lo[j] = (__bf16)(x[j] - (float)h);
  }
}

// blocks 0..31: q[b,h] = query[b,:]@Wq[h,:] + bq[h]
// blocks 32..63: split Wr into fragment-linear hi/lo bf16: [ks][mtile][lane][8]
//   element = Wr[16*mt + (l&15)][32*ks + 8*(l>>4) + j]  (A-frag layout of mfma 16x16x32)
__global__ __launch_bounds__(256) void prep_kernel(
    const float* __restrict__ query, const float* __restrict__ Wq,
    const float* __restrict__ bq, const float* __restrict__ Wr,
    float* __restrict__ ws_q, __bf16* __restrict__ wsAhi, __bf16* __restrict__ wsAlo) {
  const int tid = threadIdx.x;
  const int blk = blockIdx.x;
  if (blk < NB) {
    const float4* qr = reinterpret_cast<const float4*>(query + blk * NQ);
    const float4* wr = reinterpret_cast<const float4*>(Wq + tid * NQ);
    float acc = 0.0f;
#pragma unroll 8
    for (int i = 0; i < NQ / 4; ++i) {
      float4 a = qr[i], w = wr[i];
      acc += a.x * w.x + a.y * w.y + a.z * w.z + a.w * w.w;
    }
    ws_q[blk * NH + tid] = acc + bq[tid];
  } else {
    const int gid = (blk - NB) * 256 + tid;   // 0..8191 = [ks(8)][mt(16)][lane(64)]
    const int l  = gid & 63;
    const int mt = (gid >> 6) & 15;
    const int ks = gid >> 10;
    const int row = 16 * mt + (l & 15);
    const int kb  = 32 * ks + 8 * (l >> 4);
    const float4* src = reinterpret_cast<const float4*>(Wr + row * NR + kb);
    bf16x8 hi, lo;
    split8(src[0], src[1], hi, lo);
    *reinterpret_cast<bf16x8*>(wsAhi + (size_t)gid * 8) = hi;
    *reinterpret_cast<bf16x8*>(wsAlo + (size_t)gid * 8) = lo;
  }
}

// R5: R0 structure (single LDS buffer, 2 plain __syncthreads per k-step, LDS staging)
// with HALVED s-tile to cut registers -> 4 waves/SIMD occupancy.
// Block: batch b, 32 s-cols, all 256 h. Wave wm: h in [64wm, 64wm+64), acc 2x4 frags (32 AGPR).
__global__ __launch_bounds__(256, 4) void attn_kernel(
    const float* __restrict__ ref, const float* __restrict__ br,
    const float* __restrict__ v, const float* __restrict__ ws_q,
    const __bf16* __restrict__ wsAhi, const __bf16* __restrict__ wsAlo,
    float* __restrict__ e_out, float* __restrict__ u_out) {
  __shared__ __bf16 lXhi[2 * 64 * 8];   // frag-linear: [ntile(2)][lane(64)][8]
  __shared__ __bf16 lXlo[2 * 64 * 8];
  __shared__ float  u_part[4][32];

  const int tid = threadIdx.x;
  const int l   = tid & 63;
  const int wm  = tid >> 6;
  const int s0  = blockIdx.x * 32;
  const int b   = blockIdx.y;

  // staging decomposition: tid = nt_s*128 + ls*2 + half; thread stages 4 floats of
  // frag slot (nt_s, ls), elements 4*half..4*half+3. LDS byte offset = 8*tid (linear).
  const int nt_s = tid >> 7;
  const int ls   = (tid >> 1) & 63;
  const int half = tid & 1;
  const float* srcX = ref + (size_t)(s0 + 16 * nt_s + (ls & 15)) * (NB * NR)
                          + (size_t)b * NR + 8 * (ls >> 4) + 4 * half;

  f32x4 acc[4][2];
  const f32x4 zero = {0.f, 0.f, 0.f, 0.f};
#pragma unroll
  for (int mt = 0; mt < 4; ++mt)
#pragma unroll
    for (int nt = 0; nt < 2; ++nt) acc[mt][nt] = zero;

#pragma unroll 1
  for (int ks = 0; ks < NR / 32; ++ks) {
    // ref load first (HBM, longest latency), then A-frags (L2)
    float4 x = *reinterpret_cast<const float4*>(srcX + ks * 32);
    bf16x8 ah[4], al[4];
#pragma unroll
    for (int mt = 0; mt < 4; ++mt) {
      const size_t fo = ((size_t)(ks * 16 + wm * 4 + mt) * 64 + l) * 8;
      ah[mt] = *reinterpret_cast<const bf16x8*>(wsAhi + fo);
      al[mt] = *reinterpret_cast<const bf16x8*>(wsAlo + fo);
    }
    __syncthreads();                      // previous iter's B-frag reads done
    bf16x4 xhi, xlo;
    split4(x, xhi, xlo);
    *reinterpret_cast<bf16x4*>(lXhi + tid * 4) = xhi;
    *reinterpret_cast<bf16x4*>(lXlo + tid * 4) = xlo;
    __syncthreads();                      // tile published

    bf16x8 bh[2], bl[2];
#pragma unroll
    for (int nt = 0; nt < 2; ++nt) {      // contiguous ds_read_b128, conflict-free
      bh[nt] = *reinterpret_cast<const bf16x8*>(lXhi + (nt * 64 + l) * 8);
      bl[nt] = *reinterpret_cast<const bf16x8*>(lXlo + (nt * 64 + l) * 8);
    }
    __builtin_amdgcn_s_setprio(1);
#pragma unroll
    for (int mt = 0; mt < 4; ++mt) {
#pragma unroll
      for (int nt = 0; nt < 2; ++nt) {
        acc[mt][nt] = __builtin_amdgcn_mfma_f32_16x16x32_bf16(ah[mt], bh[nt], acc[mt][nt], 0, 0, 0);
        acc[mt][nt] = __builtin_amdgcn_mfma_f32_16x16x32_bf16(ah[mt], bl[nt], acc[mt][nt], 0, 0, 0);
        acc[mt][nt] = __builtin_amdgcn_mfma_f32_16x16x32_bf16(al[mt], bh[nt], acc[mt][nt], 0, 0, 0);
      }
    }
    __builtin_amdgcn_s_setprio(0);
  }

  // Epilogue. C/D layout (m89-verified): col = lane&15, row = 4*(lane>>4) + reg
  const int col = l & 15;
  const int rq  = l >> 4;
  float psum[2] = {0.f, 0.f};
#pragma unroll
  for (int mt = 0; mt < 4; ++mt) {
#pragma unroll
    for (int r = 0; r < 4; ++r) {
      const int h = 64 * wm + 16 * mt + 4 * rq + r;
      const float brv = br[h];
      const float qv  = ws_q[b * NH + h];
      const float vv  = v[h];
#pragma unroll
      for (int nt = 0; nt < 2; ++nt) {
        float e = acc[mt][nt][r] + brv;
        e_out[(size_t)b * NH * NS + (size_t)h * NS + (s0 + 16 * nt + col)] = e;
        psum[nt] += vv * fast_tanh(qv + e);
      }
    }
  }
  // reduce over h: butterfly over lane-quads, then cross-wave sum via LDS
#pragma unroll
  for (int nt = 0; nt < 2; ++nt) {
    float p = psum[nt];
    p += __shfl_xor(p, 16, 64);
    p += __shfl_xor(p, 32, 64);
    if (l < 16) u_part[wm][16 * nt + col] = p;
  }
  __syncthreads();
  if (tid < 32) {
    float u = u_part[0][tid] + u_part[1][tid] + u_part[2][tid] + u_part[3][tid];
    u_out[(size_t)b * NS + s0 + tid] = 10.0f * fast_tanh(u);
  }
}

extern "C" void kernel_launch(void* const* d_in, const int* in_sizes, int n_in,
                              void* d_out, int out_size, void* d_ws, size_t ws_size,
                              hipStream_t stream) {
  const float* query = (const float*)d_in[0];
  const float* ref   = (const float*)d_in[1];
  const float* Wq    = (const float*)d_in[2];
  const float* bq    = (const float*)d_in[3];
  const float* Wr    = (const float*)d_in[4];
  const float* br    = (const float*)d_in[5];
  const float* v     = (const float*)d_in[6];

  float* e_out = (float*)d_out;                       // [B][H][S]
  float* u_out = e_out + (size_t)NB * NH * NS;        // [B][S]

  // ws layout: q f32[32][256] (32 KiB) | Wr hi bf16[8192*8] (128 KiB) | Wr lo (128 KiB)
  float*  ws_q  = (float*)d_ws;
  __bf16* wsAhi = (__bf16*)((char*)d_ws + 32 * 1024);
  __bf16* wsAlo = (__bf16*)((char*)d_ws + 32 * 1024 + 128 * 1024);

  prep_kernel<<<dim3(NB + 32), 256, 0, stream>>>(query, Wq, bq, Wr, ws_q, wsAhi, wsAlo);
  attn_kernel<<<dim3(NS / 32, NB), 256, 0, stream>>>(ref, br, v, ws_q, wsAhi, wsAlo, e_out, u_out);
}

// Round 7
// 191.608 us; speedup vs baseline: 2.4617x; 1.1786x over previous
//
#include <hip/hip_runtime.h>

#define NB 32      // B
#define NS 8192    // S
#define NH 256     // H
#define NR 256     // RIN
#define NQ 256     // QIN

typedef __bf16 bf16x8 __attribute__((ext_vector_type(8)));
typedef float  f32x4  __attribute__((ext_vector_type(4)));

typedef const __attribute__((address_space(1))) void* gas_ptr;
typedef __attribute__((address_space(3))) void* las_ptr;

__device__ __forceinline__ void stage16(const float* g, void* lds) {
  // async DMA: 64 lanes x 16B; LDS dest = uniform base + lane*16 (linear)
  __builtin_amdgcn_global_load_lds((gas_ptr)(const void*)g, (las_ptr)lds, 16, 0, 0);
}

__device__ __forceinline__ float fast_tanh(float x) {
  x = fminf(15.0f, fmaxf(-15.0f, x));
  float e = __expf(2.0f * x);
  return (e - 1.0f) * __builtin_amdgcn_rcpf(e + 1.0f);
}

// split 8 consecutive f32 into bf16 hi + bf16 lo (RNE): x ~= hi + lo
__device__ __forceinline__ void split8(float4 a, float4 b, bf16x8& hi, bf16x8& lo) {
  float x[8] = {a.x, a.y, a.z, a.w, b.x, b.y, b.z, b.w};
#pragma unroll
  for (int j = 0; j < 8; ++j) {
    __bf16 h = (__bf16)x[j];
    hi[j] = h;
    lo[j] = (__bf16)(x[j] - (float)h);
  }
}

// blocks 0..31: q[b,h] = query[b,:]@Wq[h,:] + bq[h]
// blocks 32..63: split Wr into fragment-linear hi/lo bf16: [ks][mtile][lane][8]
__global__ __launch_bounds__(256) void prep_kernel(
    const float* __restrict__ query, const float* __restrict__ Wq,
    const float* __restrict__ bq, const float* __restrict__ Wr,
    float* __restrict__ ws_q, __bf16* __restrict__ wsAhi, __bf16* __restrict__ wsAlo) {
  const int tid = threadIdx.x;
  const int blk = blockIdx.x;
  if (blk < NB) {
    const float4* qr = reinterpret_cast<const float4*>(query + blk * NQ);
    const float4* wr = reinterpret_cast<const float4*>(Wq + tid * NQ);
    float acc = 0.0f;
#pragma unroll 8
    for (int i = 0; i < NQ / 4; ++i) {
      float4 a = qr[i], w = wr[i];
      acc += a.x * w.x + a.y * w.y + a.z * w.z + a.w * w.w;
    }
    ws_q[blk * NH + tid] = acc + bq[tid];
  } else {
    const int gid = (blk - NB) * 256 + tid;   // [ks(8)][mt(16)][lane(64)]
    const int l  = gid & 63;
    const int mt = (gid >> 6) & 15;
    const int ks = gid >> 10;
    const int row = 16 * mt + (l & 15);
    const int kb  = 32 * ks + 8 * (l >> 4);
    const float4* src = reinterpret_cast<const float4*>(Wr + row * NR + kb);
    bf16x8 hi, lo;
    split8(src[0], src[1], hi, lo);
    *reinterpret_cast<bf16x8*>(wsAhi + (size_t)gid * 8) = hi;
    *reinterpret_cast<bf16x8*>(wsAlo + (size_t)gid * 8) = lo;
  }
}

__device__ __forceinline__ void barrier_lgkm_only() {
  asm volatile("s_waitcnt lgkmcnt(0)" ::: "memory");
  __builtin_amdgcn_sched_barrier(0);
  __builtin_amdgcn_s_barrier();
  __builtin_amdgcn_sched_barrier(0);
}

// R6: m97-style async staging. Block: batch b, 64 s-cols, 256 h; wave wm = 64 h-rows.
// ref f32 tile (8KB/ks) staged via global_load_lds into double-buffered frag-linear LDS:
//   LDS slot (i = 2*nt + j, lane): byte = buf*8192 + i*1024 + lane*16
//   content: ref[s0 + 16*nt + (lane&15)][b][ks*32 + 8*(lane>>4) + 4*j .. +3]
// achieved by pre-permuting the per-lane GLOBAL source (DMA LDS dest is linear).
// Counted vmcnt(10) per iter (2 stage + 8 A-loads younger); no vmcnt(0) in loop.
__global__ __launch_bounds__(256, 3) void attn_kernel(
    const float* __restrict__ ref, const float* __restrict__ br,
    const float* __restrict__ v, const float* __restrict__ ws_q,
    const __bf16* __restrict__ wsAhi, const __bf16* __restrict__ wsAlo,
    float* __restrict__ e_out, float* __restrict__ u_out) {
  __shared__ float lXf[2][2048];       // 2 x 8KB ref tiles, frag-linear
  __shared__ float u_part[4][64];

  const int tid = threadIdx.x;
  const int l   = tid & 63;
  const int wm  = tid >> 6;            // wave stages slots i = 2wm, 2wm+1 (nt = wm)
  const int s0  = blockIdx.x * 64;
  const int b   = blockIdx.y;

  // per-lane global source for this wave's two DMA slots (j = 0,1):
  const float* gsrc = ref + (size_t)(s0 + 16 * wm + (l & 15)) * (NB * NR)
                          + (size_t)b * NR + 8 * (l >> 4);
  char* lbase = (char*)&lXf[0][0];

  f32x4 acc[4][4];
  const f32x4 zero = {0.f, 0.f, 0.f, 0.f};
#pragma unroll
  for (int mt = 0; mt < 4; ++mt)
#pragma unroll
    for (int nt = 0; nt < 4; ++nt) acc[mt][nt] = zero;

  // prologue: stage ks=0 into buf0
  stage16(gsrc + 0, lbase + (2 * wm + 0) * 1024);
  stage16(gsrc + 4, lbase + (2 * wm + 1) * 1024);

#pragma unroll 1
  for (int ks = 0; ks < NR / 32; ++ks) {
    const int cur = ks & 1;
    const int nxt = cur ^ 1;
    // barrier FIRST: everyone's ds_reads of buf[nxt] (iter ks-1) are done (lgkmcnt
    // before entry), so overwriting buf[nxt] below is safe.
    barrier_lgkm_only();
    // stage ks+1 into buf[nxt] (last iter: re-stage ks — harmless, keeps vmcnt uniform)
    const int ksn32 = (ks < NR / 32 - 1) ? (ks + 1) * 32 : ks * 32;
    stage16(gsrc + ksn32 + 0, lbase + (nxt * 8 + 2 * wm + 0) * 1024);
    stage16(gsrc + ksn32 + 4, lbase + (nxt * 8 + 2 * wm + 1) * 1024);
    // A-frags for ks (L2-resident pre-split Wr)
    bf16x8 ah[4], al[4];
#pragma unroll
    for (int mt = 0; mt < 4; ++mt) {
      const size_t fo = ((size_t)(ks * 16 + wm * 4 + mt) * 64 + l) * 8;
      ah[mt] = *reinterpret_cast<const bf16x8*>(wsAhi + fo);
      al[mt] = *reinterpret_cast<const bf16x8*>(wsAlo + fo);
    }
    // wait stage(cur) [issued last iter]: 10 younger VMEM ops (2 stage + 8 A) allowed
    __builtin_amdgcn_sched_barrier(0);
    asm volatile("s_waitcnt vmcnt(10)" ::: "memory");
    __builtin_amdgcn_sched_barrier(0);
    // read B source (f32) from frag-linear LDS, split to bf16 hi/lo per wave
    bf16x8 bh[4], bl[4];
#pragma unroll
    for (int nt = 0; nt < 4; ++nt) {
      float4 x0 = *reinterpret_cast<const float4*>(&lXf[cur][(2 * nt + 0) * 256 + l * 4]);
      float4 x1 = *reinterpret_cast<const float4*>(&lXf[cur][(2 * nt + 1) * 256 + l * 4]);
      split8(x0, x1, bh[nt], bl[nt]);
    }
    __builtin_amdgcn_s_setprio(1);
#pragma unroll
    for (int mt = 0; mt < 4; ++mt) {
#pragma unroll
      for (int nt = 0; nt < 4; ++nt) {
        acc[mt][nt] = __builtin_amdgcn_mfma_f32_16x16x32_bf16(ah[mt], bh[nt], acc[mt][nt], 0, 0, 0);
        acc[mt][nt] = __builtin_amdgcn_mfma_f32_16x16x32_bf16(ah[mt], bl[nt], acc[mt][nt], 0, 0, 0);
        acc[mt][nt] = __builtin_amdgcn_mfma_f32_16x16x32_bf16(al[mt], bh[nt], acc[mt][nt], 0, 0, 0);
      }
    }
    __builtin_amdgcn_s_setprio(0);
  }

  // Epilogue. C/D layout: col = lane&15, row = 4*(lane>>4) + reg
  const int col = l & 15;
  const int rq  = l >> 4;
  float psum[4] = {0.f, 0.f, 0.f, 0.f};
#pragma unroll
  for (int mt = 0; mt < 4; ++mt) {
#pragma unroll
    for (int r = 0; r < 4; ++r) {
      const int h = 64 * wm + 16 * mt + 4 * rq + r;
      const float brv = br[h];
      const float qv  = ws_q[b * NH + h];
      const float vv  = v[h];
#pragma unroll
      for (int nt = 0; nt < 4; ++nt) {
        float e = acc[mt][nt][r] + brv;
        e_out[(size_t)b * NH * NS + (size_t)h * NS + (s0 + 16 * nt + col)] = e;
        psum[nt] += vv * fast_tanh(qv + e);
      }
    }
  }
#pragma unroll
  for (int nt = 0; nt < 4; ++nt) {
    float p = psum[nt];
    p += __shfl_xor(p, 16, 64);
    p += __shfl_xor(p, 32, 64);
    if (l < 16) u_part[wm][16 * nt + col] = p;
  }
  barrier_lgkm_only();   // publish u_part; e-stores stay in flight
  if (tid < 64) {
    float u = u_part[0][tid] + u_part[1][tid] + u_part[2][tid] + u_part[3][tid];
    u_out[(size_t)b * NS + s0 + tid] = 10.0f * fast_tanh(u);
  }
}

extern "C" void kernel_launch(void* const* d_in, const int* in_sizes, int n_in,
                              void* d_out, int out_size, void* d_ws, size_t ws_size,
                              hipStream_t stream) {
  const float* query = (const float*)d_in[0];
  const float* ref   = (const float*)d_in[1];
  const float* Wq    = (const float*)d_in[2];
  const float* bq    = (const float*)d_in[3];
  const float* Wr    = (const float*)d_in[4];
  const float* br    = (const float*)d_in[5];
  const float* v     = (const float*)d_in[6];

  float* e_out = (float*)d_out;                       // [B][H][S]
  float* u_out = e_out + (size_t)NB * NH * NS;        // [B][S]

  float*  ws_q  = (float*)d_ws;
  __bf16* wsAhi = (__bf16*)((char*)d_ws + 32 * 1024);
  __bf16* wsAlo = (__bf16*)((char*)d_ws + 32 * 1024 + 128 * 1024);

  prep_kernel<<<dim3(NB + 32), 256, 0, stream>>>(query, Wq, bq, Wr, ws_q, wsAhi, wsAlo);
  attn_kernel<<<dim3(NS / 64, NB), 256, 0, stream>>>(ref, br, v, ws_q, wsAhi, wsAlo, e_out, u_out);
}